// Round 18
// baseline (279.153 us; speedup 1.0000x reference)
//
#include <hip/hip_runtime.h>
#include <hip/hip_bf16.h>

// MHSA: B=4, P=4096, C=256, H=4, D=64. fp32 in/out, bf16 MFMA internally.
#define DIMC 256
#define NHEADS 4
#define HDIM 64
#define BATCH 4
#define SEQ 4096
#define MTOT (BATCH*SEQ)   // 16384
#define SCALE_LOG2E 0.18033688011112042f  // 0.125 * log2(e); softmax done in exp2 domain

typedef __attribute__((ext_vector_type(8))) __bf16 bf16x8;
typedef __attribute__((ext_vector_type(4))) __bf16 bf16x4;
typedef __attribute__((ext_vector_type(2))) __bf16 bf16x2;
typedef __attribute__((ext_vector_type(4))) float f32x4;
typedef __attribute__((ext_vector_type(16))) float f32x16;
typedef __attribute__((ext_vector_type(2))) unsigned uint2v;
typedef __attribute__((ext_vector_type(4))) unsigned uint4v;

__device__ inline void gll16(const void* g, void* l) {
  // async global->LDS, 16B per lane. LDS dest must be wave-uniform base + lane*16.
  __builtin_amdgcn_global_load_lds((const __attribute__((address_space(1))) unsigned int*)g,
                                   (__attribute__((address_space(3))) unsigned int*)l, 16, 0, 0);
}

// Single v_exp_f32 via the compiler intrinsic (R5 lesson: never raw asm TRANS ops).
__device__ inline float vexp2(float x) { return __builtin_amdgcn_exp2f(x); }

// Pack two f32 -> one u32 of 2 bf16 (RNE). Plain casts (NOT inline asm).
__device__ inline unsigned pack2(float lo, float hi) {
  bf16x2 p; p[0] = (__bf16)lo; p[1] = (__bf16)hi;
  return __builtin_bit_cast(unsigned, p);
}

// Swizzled read from a 64-bf16-row (128B) LDS tile: chunk' = c16 ^ (row&7).
// R16 null-result lesson: with 128B rows the row index CANNOT affect bank
// selection (row*128 ≡ 0 mod 32-bank wrap); the residual ~4 cyc/b128-read is
// inherent to the access shape. Fix is fewer reads per MFMA (R17), not XOR form.
__device__ inline bf16x8 swzread(const __bf16* base, int row, int c16) {
  return *reinterpret_cast<const bf16x8*>(
      reinterpret_cast<const char*>(base) + row * 128 + ((c16 ^ (row & 7)) << 4));
}

// ---------------- prep kernels ----------------

__global__ __launch_bounds__(256) void cvt_x_kernel(const float* __restrict__ x, __bf16* __restrict__ xb) {
  int i = (blockIdx.x * 256 + threadIdx.x) * 4;
  float4 v = *reinterpret_cast<const float4*>(x + i);
  bf16x4 o;
  o[0] = (__bf16)v.x; o[1] = (__bf16)v.y; o[2] = (__bf16)v.z; o[3] = (__bf16)v.w;
  *reinterpret_cast<bf16x4*>(xb + i) = o;
}

// Builds Wqkv^T [768][256] (Wq scaled by 0.125*log2e), Wo^T [256][256], and
// (rows 1024..1026) the scaled/merged qkv bias.
__global__ __launch_bounds__(256) void prep_w(const float* __restrict__ Wq, const float* __restrict__ Wk,
                                              const float* __restrict__ Wv, const float* __restrict__ Wo,
                                              const float* __restrict__ bq, const float* __restrict__ bk,
                                              const float* __restrict__ bv,
                                              __bf16* __restrict__ wqkvt, __bf16* __restrict__ wot,
                                              float* __restrict__ biasq) {
  int row = blockIdx.x;        // 0..1026
  int k = threadIdx.x;         // 0..255
  if (row < 768) {
    const float* src; float scale = 1.f; int n = row & 255;
    if (row < 256)      { src = Wq; scale = SCALE_LOG2E; }
    else if (row < 512) { src = Wk; }
    else                { src = Wv; }
    wqkvt[row * 256 + k] = (__bf16)(src[k * 256 + n] * scale);
  } else if (row < 1024) {
    int n = row - 768;
    wot[n * 256 + k] = (__bf16)(Wo[k * 256 + n]);
  } else {
    int i = (row - 1024) * 256 + k;   // 0..767
    biasq[i] = (i < 256) ? bq[i] * SCALE_LOG2E : (i < 512 ? bk[i - 256] : bv[i - 512]);
  }
}

// ---------------- GEMM: C[m][n] = sum_k A[m][k]*Bt[n][k] + bias[n] ----------------
// 128x128 tile, BK=64, 4 waves (2x2 of 64x64), mfma 16x16x32 bf16. T2-swizzled LDS.
// Pure gll16 staging for BOTH operands (R12 lesson: fp32 reg-staging of A cost
// ~16 µs — async global_load_lds is worth more than fusing the cvt).
// MODE 0: scatter q/k into [bh][p][d] and V directly transposed into vt [bh][d][p].
// MODE 1: fp32 out [m][256].
template<int MODE>
__global__ __launch_bounds__(256) void gemm_bt(const __bf16* __restrict__ A, const __bf16* __restrict__ Bt,
                                               const float* __restrict__ bias,
                                               __bf16* __restrict__ q_ws, __bf16* __restrict__ k_ws,
                                               __bf16* __restrict__ vt_ws, float* __restrict__ fout) {
  __shared__ __align__(16) __bf16 As[128 * 64];
  __shared__ __align__(16) __bf16 Bs[128 * 64];
  const int tid = threadIdx.x;
  const int lane = tid & 63, wave = tid >> 6;
  const int wr = wave >> 1, wc = wave & 1;
  const int r16 = lane & 15, g4 = lane >> 4;
  const int m0 = blockIdx.y * 128, n0 = blockIdx.x * 128;
  f32x4 acc[4][4] = {};
  for (int k0 = 0; k0 < DIMC; k0 += 64) {
    #pragma unroll
    for (int it = 0; it < 4; ++it) {
      int e = it * 256 + tid;           // 16B chunk id
      int r = e >> 3, c = e & 7;
      int cs = c ^ (r & 7);             // pre-swizzled source column (rule #21)
      gll16(A  + (size_t)(m0 + r) * DIMC + k0 + cs * 8, As + e * 8);
      gll16(Bt + (size_t)(n0 + r) * DIMC + k0 + cs * 8, Bs + e * 8);
    }
    __syncthreads();
    #pragma unroll
    for (int kk = 0; kk < 2; ++kk) {
      bf16x8 af[4], bfr[4];
      #pragma unroll
      for (int mi = 0; mi < 4; ++mi)
        af[mi] = swzread(As, wr * 64 + mi * 16 + r16, kk * 4 + g4);
      #pragma unroll
      for (int ni = 0; ni < 4; ++ni)
        bfr[ni] = swzread(Bs, wc * 64 + ni * 16 + r16, kk * 4 + g4);
      #pragma unroll
      for (int mi = 0; mi < 4; ++mi)
        #pragma unroll
        for (int ni = 0; ni < 4; ++ni)
          acc[mi][ni] = __builtin_amdgcn_mfma_f32_16x16x32_bf16(af[mi], bfr[ni], acc[mi][ni], 0, 0, 0);
    }
    __syncthreads();
  }
  // Epilogue. C/D layout: col = lane&15, row = (lane>>4)*4 + reg.
  #pragma unroll
  for (int mi = 0; mi < 4; ++mi)
    #pragma unroll
    for (int ni = 0; ni < 4; ++ni)
      #pragma unroll
      for (int r = 0; r < 4; ++r) {
        int m = m0 + wr * 64 + mi * 16 + g4 * 4 + r;
        int n = n0 + wc * 64 + ni * 16 + r16;
        float v = acc[mi][ni][r] + bias[n];
        if (MODE == 0) {
          int b = m >> 12, p = m & 4095;
          int sect = n >> 8, nc = n & 255;
          int h = nc >> 6, d = nc & 63;
          __bf16 hv = (__bf16)v;
          size_t bhb = (size_t)(b * NHEADS + h);
          if (sect == 0)      q_ws[(bhb * SEQ + p) * HDIM + d] = hv;
          else if (sect == 1) k_ws[(bhb * SEQ + p) * HDIM + d] = hv;
          else                vt_ws[(bhb * HDIM + d) * SEQ + p] = hv;  // direct V^T
        } else {
          fout[(size_t)m * DIMC + n] = v;
        }
      }
}

// ---------------- flash attention (split-KV x4, NO atomics, 64 q/wave) ----------------
// R17: each wave owns TWO 32-q sub-tiles (q-tile 256 = 4 waves x 64q); every
// kf/vf LDS read feeds 2 MFMAs -> LDS reads/MFMA and barriers/MFMA HALVE
// (R16 showed the per-read conflict cost is inherent to the b128 shape).
// VGPR-budgeted for (256,3) cap ~170: o_acc 64 + qf 32 + pa 32 + transient
// s 32 (exp'd IN PLACE, ni-sequential) + dv 8 + misc ~12 ≈ 164.
// Split-KV x4: quarters 0,1 -> ws partials; quarters 2,3 -> d_out region
// (fully rewritten by gemm1 afterwards). Plain stores, no atomics.
//   S^T = K Q^T: D col=lane&31=q, row kv=(r&3)+8*(r>>2)+4*(lane>>5)+32*ni [m74/m101].
//   p32swap semantics (R7-validated): d0={a.lo32,b.lo32}, d1={a.hi32,b.hi32}.
__global__ __launch_bounds__(256, 3) void attn_kernel(const __bf16* __restrict__ q_ws, const __bf16* __restrict__ k_ws,
                                                      const __bf16* __restrict__ vt_ws,
                                                      __bf16* __restrict__ o01, __bf16* __restrict__ o23,
                                                      float* __restrict__ lsum_part) {
  __shared__ __align__(16) __bf16 Ks[2][64 * 64];   // [kv][d], swizzled
  __shared__ __align__(16) __bf16 Vts[2][64 * 64];  // [d][kv], swizzled
  const int tid = threadIdx.x;
  const int lane = tid & 63;
  const int l31 = lane & 31, h5 = lane >> 5;
  // XCD-bijective swizzle over 1024 blocks: 128 consecutive wgs (2 heads) per XCD.
  int bid = blockIdx.x;
  int wg = (bid & 7) * 128 + (bid >> 3);
  int bh = wg >> 6, sub = wg & 63;
  int qb = sub >> 2, quarter = sub & 3;
  int b = bh >> 2, h = bh & 3;
  const __bf16* Qp  = q_ws  + (size_t)bh * SEQ * HDIM;
  const __bf16* Kp  = k_ws  + (size_t)bh * SEQ * HDIM;
  const __bf16* Vtp = vt_ws + (size_t)bh * HDIM * SEQ;
  const int q0 = qb * 256 + (tid >> 6) * 64;        // wave owns q0..q0+63
  const int kvb = quarter * (SEQ / 4);
  // Q B-frags for both halves: col=lane&31=q, k = ks*16 + h5*8 + j
  bf16x8 qf[2][4];
  #pragma unroll
  for (int hh = 0; hh < 2; ++hh)
    #pragma unroll
    for (int ks = 0; ks < 4; ++ks)
      qf[hh][ks] = *reinterpret_cast<const bf16x8*>(Qp + (size_t)(q0 + hh * 32 + l31) * HDIM + ks * 16 + h5 * 8);
  f32x16 o_acc[2][2] = {};            // [half][di]
  f32x4 dv0 = {}, dv1 = {};           // per-half independent denominator chains

  // staging: 256 threads x 2 chunks x (16B K + 16B Vt); pre-swizzled source col.
  const int sr = tid >> 3;
  const int scs = (tid & 7) ^ (sr & 7);
  const __bf16* kSrc = Kp  + (size_t)sr * HDIM + scs * 8;
  const __bf16* vSrc = Vtp + (size_t)sr * SEQ  + scs * 8;

  #define STAGE(buf, kv0) do { \
      gll16(kSrc + (size_t)(kv0) * HDIM,        &Ks[buf][tid * 8]); \
      gll16(kSrc + (size_t)((kv0) + 32) * HDIM, &Ks[buf][(tid + 256) * 8]); \
      gll16(vSrc + (kv0),                       &Vts[buf][tid * 8]); \
      gll16(vSrc + 32 * SEQ + (kv0),            &Vts[buf][(tid + 256) * 8]); \
    } while (0)

  // One KV tile, compile-time buffer index. ni-sequential S to cap VGPR:
  // QK(ni) -> exp in place -> pack pa[*][2ni..2ni+1] -> s regs die.
  #define TILE(BUF, DO_STAGE, kv0_next) do { \
    if (DO_STAGE) STAGE(BUF ^ 1, kv0_next); \
    bf16x8 pa0[4], pa1[4]; \
    _Pragma("unroll") \
    for (int ni = 0; ni < 2; ++ni) { \
      f32x16 s0 = {}, s1 = {}; \
      __builtin_amdgcn_s_setprio(1); \
      _Pragma("unroll") \
      for (int ks = 0; ks < 4; ++ks) { \
        bf16x8 kf = swzread(Ks[BUF], ni * 32 + l31, ks * 2 + h5); \
        s0 = __builtin_amdgcn_mfma_f32_32x32x16_bf16(kf, qf[0][ks], s0, 0, 0, 0); \
        s1 = __builtin_amdgcn_mfma_f32_32x32x16_bf16(kf, qf[1][ks], s1, 0, 0, 0); \
      } \
      __builtin_amdgcn_s_setprio(0); \
      _Pragma("unroll") \
      for (int r = 0; r < 16; ++r) { \
        s0[r] = vexp2(s0[r]); dv0[r & 3] += s0[r]; \
        s1[r] = vexp2(s1[r]); dv1[r & 3] += s1[r]; \
      } \
      _Pragma("unroll") \
      for (int u = 0; u < 2; ++u) { \
        const int base = u * 8, ks2 = ni * 2 + u; \
        { \
          unsigned A0 = pack2(s0[base + 0], s0[base + 1]); \
          unsigned A1 = pack2(s0[base + 2], s0[base + 3]); \
          unsigned B0 = pack2(s0[base + 4], s0[base + 5]); \
          unsigned B1 = pack2(s0[base + 6], s0[base + 7]); \
          uint2v r0v = __builtin_amdgcn_permlane32_swap(A0, B0, false, false); \
          uint2v r1v = __builtin_amdgcn_permlane32_swap(A1, B1, false, false); \
          uint4v wv = {r0v[0], r1v[0], r0v[1], r1v[1]}; \
          pa0[ks2] = __builtin_bit_cast(bf16x8, wv); \
        } \
        { \
          unsigned A0 = pack2(s1[base + 0], s1[base + 1]); \
          unsigned A1 = pack2(s1[base + 2], s1[base + 3]); \
          unsigned B0 = pack2(s1[base + 4], s1[base + 5]); \
          unsigned B1 = pack2(s1[base + 6], s1[base + 7]); \
          uint2v r0v = __builtin_amdgcn_permlane32_swap(A0, B0, false, false); \
          uint2v r1v = __builtin_amdgcn_permlane32_swap(A1, B1, false, false); \
          uint4v wv = {r0v[0], r1v[0], r0v[1], r1v[1]}; \
          pa1[ks2] = __builtin_bit_cast(bf16x8, wv); \
        } \
      } \
    } \
    __builtin_amdgcn_s_setprio(1); \
    _Pragma("unroll") \
    for (int ks = 0; ks < 4; ++ks) \
      _Pragma("unroll") \
      for (int di = 0; di < 2; ++di) { \
        bf16x8 vf = swzread(Vts[BUF], di * 32 + l31, ks * 2 + h5); \
        o_acc[0][di] = __builtin_amdgcn_mfma_f32_32x32x16_bf16(pa0[ks], vf, o_acc[0][di], 0, 0, 0); \
        o_acc[1][di] = __builtin_amdgcn_mfma_f32_32x32x16_bf16(pa1[ks], vf, o_acc[1][di], 0, 0, 0); \
      } \
    __builtin_amdgcn_s_setprio(0); \
    __syncthreads(); \
  } while (0)

  STAGE(0, kvb);
  __syncthreads();

  const int NT = SEQ / 4 / 64;         // 16 tiles of 64 kv per quarter
  for (int tt = 0; tt < NT; tt += 2) {
    TILE(0, true,           kvb + (tt + 1) * 64);
    TILE(1, (tt + 2) < NT,  kvb + (tt + 2) * 64);
  }

  // outputs: quarter q -> buffer (o01 for 0,1 ; o23 for 2,3), plain stores.
  __bf16* op = (quarter < 2 ? o01 : o23) + (size_t)(quarter & 1) * MTOT * DIMC;
  float* lp = lsum_part + (size_t)quarter * 16 * SEQ + (size_t)bh * SEQ;
  #pragma unroll
  for (int hh = 0; hh < 2; ++hh) {
    const f32x4& dvh = hh ? dv1 : dv0;
    float den = (dvh[0] + dvh[1]) + (dvh[2] + dvh[3]);
    den += __shfl_xor(den, 32);
    if (lane < 32) lp[q0 + hh * 32 + l31] = den;
    #pragma unroll
    for (int di = 0; di < 2; ++di)
      #pragma unroll
      for (int r = 0; r < 16; ++r) {
        int q = q0 + hh * 32 + (r & 3) + 8 * (r >> 2) + 4 * h5;
        op[(size_t)(b * SEQ + q) * DIMC + h * HDIM + di * 32 + l31] = (__bf16)o_acc[hh][di][r];
      }
  }
}

// ---------------- combine: o_ws = (o0+o1+o2+o3) / (l0+l1+l2+l3), bf16 ----------------
__global__ __launch_bounds__(256) void combine_o(const __bf16* __restrict__ o01, const __bf16* __restrict__ o23,
                                                 const float* __restrict__ lsum_part,
                                                 __bf16* __restrict__ o_ws) {
  int i = blockIdx.x * 256 + threadIdx.x;
  int flat = i * 8;
  int m = flat >> 8, c = flat & 255;
  int h = c >> 6;
  int b = m >> 12, p = m & 4095;
  size_t bhp = (size_t)(b * NHEADS + h) * SEQ + p;
  float l = 0.f;
  #pragma unroll
  for (int qr = 0; qr < 4; ++qr) l += lsum_part[(size_t)qr * 16 * SEQ + bhp];
  float inv = 1.f / l;
  bf16x8 a0 = *reinterpret_cast<const bf16x8*>(o01 + flat);
  bf16x8 a1 = *reinterpret_cast<const bf16x8*>(o01 + (size_t)MTOT * DIMC + flat);
  bf16x8 a2 = *reinterpret_cast<const bf16x8*>(o23 + flat);
  bf16x8 a3 = *reinterpret_cast<const bf16x8*>(o23 + (size_t)MTOT * DIMC + flat);
  bf16x8 o;
  #pragma unroll
  for (int j = 0; j < 8; ++j)
    o[j] = (__bf16)((((float)a0[j] + (float)a1[j]) + ((float)a2[j] + (float)a3[j])) * inv);
  *reinterpret_cast<bf16x8*>(o_ws + flat) = o;
}

// ---------------- launch ----------------

extern "C" void kernel_launch(void* const* d_in, const int* in_sizes, int n_in,
                              void* d_out, int out_size, void* d_ws, size_t ws_size,
                              hipStream_t stream) {
  const float* x  = (const float*)d_in[0];
  const float* Wq = (const float*)d_in[1];
  const float* bq = (const float*)d_in[2];
  const float* Wk = (const float*)d_in[3];
  const float* bk = (const float*)d_in[4];
  const float* Wv = (const float*)d_in[5];
  const float* bv = (const float*)d_in[6];
  const float* Wo = (const float*)d_in[7];
  const float* bo = (const float*)d_in[8];
  float* out = (float*)d_out;

  const size_t NE = (size_t)MTOT * DIMC;  // 4,194,304 elements
  char* w = (char*)d_ws;
  __bf16* q_ws   = (__bf16*)w; w += NE * 2;
  __bf16* k_ws   = (__bf16*)w; w += NE * 2;
  __bf16* vt_ws  = (__bf16*)w; w += NE * 2;
  __bf16* wqkvt  = (__bf16*)w; w += (size_t)768 * 256 * 2;
  __bf16* wot    = (__bf16*)w; w += (size_t)256 * 256 * 2;
  float*  biasq  = (float*)w;  w += 768 * 4;
  float*  lsum_p = (float*)w;  w += (size_t)4 * 16 * SEQ * 4;  // 1 MB, plain stores
  __bf16* o01    = (__bf16*)w; w += 2 * NE * 2;                // 16 MB bf16 partials (q 0,1)
  // quarters 2,3 live in d_out (16 MB, fully rewritten by gemm1 afterwards).
  __bf16* o23 = (__bf16*)out;
  // aliases: xb lives in o01 (dead before attn writes); o_ws reuses q_ws.
  __bf16* xb   = o01;
  __bf16* o_ws = q_ws;
  // total ws used: ~41.8 MB; NO memset needed (all buffers fully written).

  cvt_x_kernel<<<MTOT * DIMC / 1024, 256, 0, stream>>>(x, xb);
  prep_w<<<1027, 256, 0, stream>>>(Wq, Wk, Wv, Wo, bq, bk, bv, wqkvt, wot, biasq);
  gemm_bt<0><<<dim3(6, 128), 256, 0, stream>>>(xb, wqkvt, biasq, q_ws, k_ws, vt_ws, nullptr);
  attn_kernel<<<1024, 256, 0, stream>>>(q_ws, k_ws, vt_ws, o01, o23, lsum_p);
  combine_o<<<NE / 2048, 256, 0, stream>>>(o01, o23, lsum_p, o_ws);
  gemm_bt<1><<<dim3(2, 128), 256, 0, stream>>>(o_ws, wot, bo, nullptr, nullptr, nullptr, out);
}

// Round 19
// 126.520 us; speedup vs baseline: 2.2064x; 2.2064x over previous
//
#include <hip/hip_runtime.h>
#include <hip/hip_bf16.h>

// MHSA: B=4, P=4096, C=256, H=4, D=64. fp32 in/out, bf16 MFMA internally.
#define DIMC 256
#define NHEADS 4
#define HDIM 64
#define BATCH 4
#define SEQ 4096
#define MTOT (BATCH*SEQ)   // 16384
#define SCALE_LOG2E 0.18033688011112042f  // 0.125 * log2(e); softmax done in exp2 domain

typedef __attribute__((ext_vector_type(8))) __bf16 bf16x8;
typedef __attribute__((ext_vector_type(4))) __bf16 bf16x4;
typedef __attribute__((ext_vector_type(2))) __bf16 bf16x2;
typedef __attribute__((ext_vector_type(4))) float f32x4;
typedef __attribute__((ext_vector_type(16))) float f32x16;
typedef __attribute__((ext_vector_type(2))) unsigned uint2v;
typedef __attribute__((ext_vector_type(4))) unsigned uint4v;

__device__ inline void gll16(const void* g, void* l) {
  // async global->LDS, 16B per lane. LDS dest must be wave-uniform base + lane*16.
  __builtin_amdgcn_global_load_lds((const __attribute__((address_space(1))) unsigned int*)g,
                                   (__attribute__((address_space(3))) unsigned int*)l, 16, 0, 0);
}

// Single v_exp_f32 via the compiler intrinsic (R5 lesson: never raw asm TRANS ops).
__device__ inline float vexp2(float x) { return __builtin_amdgcn_exp2f(x); }

// Pack two f32 -> one u32 of 2 bf16 (RNE). Plain casts (NOT inline asm).
__device__ inline unsigned pack2(float lo, float hi) {
  bf16x2 p; p[0] = (__bf16)lo; p[1] = (__bf16)hi;
  return __builtin_bit_cast(unsigned, p);
}

// Swizzled read from a 64-bf16-row (128B) LDS tile: chunk' = c16 ^ (row&7).
// R16 lesson: with 128B rows the row index cannot affect bank selection
// (row*128 ≡ 0 mod bank wrap); residual b128 cost is shape-inherent.
__device__ inline bf16x8 swzread(const __bf16* base, int row, int c16) {
  return *reinterpret_cast<const bf16x8*>(
      reinterpret_cast<const char*>(base) + row * 128 + ((c16 ^ (row & 7)) << 4));
}

// R16 attn variant (kept: proven 84.6 µs config).
__device__ inline bf16x8 swzreadA(const __bf16* base, int row, int c16) {
  return *reinterpret_cast<const bf16x8*>(
      reinterpret_cast<const char*>(base) + row * 128 + ((c16 ^ ((row >> 2) & 7)) << 4));
}

// ---------------- merged prep kernel (R18: cvt_x + prep_w in one dispatch) ----------------
// Blocks 0..4095: convert x (fp32 -> bf16, 1024 elems/block).
// Blocks 4096..5122: build Wqkv^T [768][256] (Wq scaled), Wo^T, merged bias.
__global__ __launch_bounds__(256) void prep_all(const float* __restrict__ x, __bf16* __restrict__ xb,
                                                const float* __restrict__ Wq, const float* __restrict__ Wk,
                                                const float* __restrict__ Wv, const float* __restrict__ Wo,
                                                const float* __restrict__ bq, const float* __restrict__ bk,
                                                const float* __restrict__ bv,
                                                __bf16* __restrict__ wqkvt, __bf16* __restrict__ wot,
                                                float* __restrict__ biasq) {
  if (blockIdx.x < 4096) {
    int i = (blockIdx.x * 256 + threadIdx.x) * 4;
    float4 v = *reinterpret_cast<const float4*>(x + i);
    bf16x4 o;
    o[0] = (__bf16)v.x; o[1] = (__bf16)v.y; o[2] = (__bf16)v.z; o[3] = (__bf16)v.w;
    *reinterpret_cast<bf16x4*>(xb + i) = o;
    return;
  }
  int row = blockIdx.x - 4096;  // 0..1026
  int k = threadIdx.x;          // 0..255
  if (row < 768) {
    const float* src; float scale = 1.f; int n = row & 255;
    if (row < 256)      { src = Wq; scale = SCALE_LOG2E; }
    else if (row < 512) { src = Wk; }
    else                { src = Wv; }
    wqkvt[row * 256 + k] = (__bf16)(src[k * 256 + n] * scale);
  } else if (row < 1024) {
    int n = row - 768;
    wot[n * 256 + k] = (__bf16)(Wo[k * 256 + n]);
  } else {
    int i = (row - 1024) * 256 + k;   // 0..767
    biasq[i] = (i < 256) ? bq[i] * SCALE_LOG2E : (i < 512 ? bk[i - 256] : bv[i - 512]);
  }
}

// ---------------- GEMM: C[m][n] = sum_k A[m][k]*Bt[n][k] + bias[n] ----------------
// 128x128 tile, BK=64, 4 waves (2x2 of 64x64), mfma 16x16x32 bf16. T2-swizzled LDS.
// Pure gll16 staging for BOTH operands (R12 lesson: fp32 reg-staging cost ~16 µs).
// MODE 0: scatter q/k into [bh][p][d] and V directly transposed into vt [bh][d][p].
// MODE 1: fp32 out [m][256].
template<int MODE>
__global__ __launch_bounds__(256) void gemm_bt(const __bf16* __restrict__ A, const __bf16* __restrict__ Bt,
                                               const float* __restrict__ bias,
                                               __bf16* __restrict__ q_ws, __bf16* __restrict__ k_ws,
                                               __bf16* __restrict__ vt_ws, float* __restrict__ fout) {
  __shared__ __align__(16) __bf16 As[128 * 64];
  __shared__ __align__(16) __bf16 Bs[128 * 64];
  const int tid = threadIdx.x;
  const int lane = tid & 63, wave = tid >> 6;
  const int wr = wave >> 1, wc = wave & 1;
  const int r16 = lane & 15, g4 = lane >> 4;
  const int m0 = blockIdx.y * 128, n0 = blockIdx.x * 128;
  f32x4 acc[4][4] = {};
  for (int k0 = 0; k0 < DIMC; k0 += 64) {
    #pragma unroll
    for (int it = 0; it < 4; ++it) {
      int e = it * 256 + tid;           // 16B chunk id
      int r = e >> 3, c = e & 7;
      int cs = c ^ (r & 7);             // pre-swizzled source column (rule #21)
      gll16(A  + (size_t)(m0 + r) * DIMC + k0 + cs * 8, As + e * 8);
      gll16(Bt + (size_t)(n0 + r) * DIMC + k0 + cs * 8, Bs + e * 8);
    }
    __syncthreads();
    #pragma unroll
    for (int kk = 0; kk < 2; ++kk) {
      bf16x8 af[4], bfr[4];
      #pragma unroll
      for (int mi = 0; mi < 4; ++mi)
        af[mi] = swzread(As, wr * 64 + mi * 16 + r16, kk * 4 + g4);
      #pragma unroll
      for (int ni = 0; ni < 4; ++ni)
        bfr[ni] = swzread(Bs, wc * 64 + ni * 16 + r16, kk * 4 + g4);
      #pragma unroll
      for (int mi = 0; mi < 4; ++mi)
        #pragma unroll
        for (int ni = 0; ni < 4; ++ni)
          acc[mi][ni] = __builtin_amdgcn_mfma_f32_16x16x32_bf16(af[mi], bfr[ni], acc[mi][ni], 0, 0, 0);
    }
    __syncthreads();
  }
  // Epilogue. C/D layout: col = lane&15, row = (lane>>4)*4 + reg.
  #pragma unroll
  for (int mi = 0; mi < 4; ++mi)
    #pragma unroll
    for (int ni = 0; ni < 4; ++ni)
      #pragma unroll
      for (int r = 0; r < 4; ++r) {
        int m = m0 + wr * 64 + mi * 16 + g4 * 4 + r;
        int n = n0 + wc * 64 + ni * 16 + r16;
        float v = acc[mi][ni][r] + bias[n];
        if (MODE == 0) {
          int b = m >> 12, p = m & 4095;
          int sect = n >> 8, nc = n & 255;
          int h = nc >> 6, d = nc & 63;
          __bf16 hv = (__bf16)v;
          size_t bhb = (size_t)(b * NHEADS + h);
          if (sect == 0)      q_ws[(bhb * SEQ + p) * HDIM + d] = hv;
          else if (sect == 1) k_ws[(bhb * SEQ + p) * HDIM + d] = hv;
          else                vt_ws[(bhb * HDIM + d) * SEQ + p] = hv;  // direct V^T
        } else {
          fout[(size_t)m * DIMC + n] = v;
        }
      }
}

// ---------------- flash attention (split-KV x2, NO atomics) — EXACT R16 ----------------
// Proven 84.6 µs. 32x32x16 core, dv[4] denominator chains, compile-time
// double-buffer unroll, bf16 partial-O plain stores + combine after.
// R17 lesson: 64-q/wave variant spills (>128 VGPR) — do not regraft without
// a ground-up register plan.
__global__ __launch_bounds__(256, 4) void attn_kernel(const __bf16* __restrict__ q_ws, const __bf16* __restrict__ k_ws,
                                                      const __bf16* __restrict__ vt_ws,
                                                      __bf16* __restrict__ o_part, float* __restrict__ lsum_part) {
  __shared__ __align__(16) __bf16 Ks[2][64 * 64];   // [kv][d], swizzled (f = (r>>2)&7)
  __shared__ __align__(16) __bf16 Vts[2][64 * 64];  // [d][kv], swizzled (f = (r>>2)&7)
  const int tid = threadIdx.x;
  const int lane = tid & 63;
  const int l31 = lane & 31, h5 = lane >> 5;
  // XCD-bijective swizzle over 1024 blocks: 128 consecutive wgs (2 heads) per XCD.
  int bid = blockIdx.x;
  int wg = (bid & 7) * 128 + (bid >> 3);
  int bh = wg >> 6, rrw = wg & 63;
  int qb = rrw >> 1, half = rrw & 1;
  int b = bh >> 2, h = bh & 3;
  const __bf16* Qp  = q_ws  + (size_t)bh * SEQ * HDIM;
  const __bf16* Kp  = k_ws  + (size_t)bh * SEQ * HDIM;
  const __bf16* Vtp = vt_ws + (size_t)bh * HDIM * SEQ;
  const int q0 = qb * 128 + (tid >> 6) * 32;
  const int kvb = half * (SEQ / 2);
  // Q B-frag: col=lane&31=q, k = ks*16 + h5*8 + j
  bf16x8 qf[4];
  #pragma unroll
  for (int ks = 0; ks < 4; ++ks)
    qf[ks] = *reinterpret_cast<const bf16x8*>(Qp + (size_t)(q0 + l31) * HDIM + ks * 16 + h5 * 8);
  f32x16 o_acc[2] = {};
  f32x4 dv = {};                      // 4 independent denominator chains (R14)

  // staging: source octet permuted within row by f(sr) = (sr>>2)&7;
  // ((sr+32)>>2)&7 == (sr>>2)&7 so one base serves both gll16 rows.
  const int sr = tid >> 3;
  const int scs = (tid & 7) ^ ((sr >> 2) & 7);
  const __bf16* kSrc = Kp  + (size_t)sr * HDIM + scs * 8;
  const __bf16* vSrc = Vtp + (size_t)sr * SEQ  + scs * 8;

  #define STAGE(buf, kv0) do { \
      gll16(kSrc + (size_t)(kv0) * HDIM,        &Ks[buf][tid * 8]); \
      gll16(kSrc + (size_t)((kv0) + 32) * HDIM, &Ks[buf][(tid + 256) * 8]); \
      gll16(vSrc + (kv0),                       &Vts[buf][tid * 8]); \
      gll16(vSrc + 32 * SEQ + (kv0),            &Vts[buf][(tid + 256) * 8]); \
    } while (0)

  #define TILE(BUF, DO_STAGE, kv0_next) do { \
    if (DO_STAGE) STAGE(BUF ^ 1, kv0_next); \
    f32x16 s[2] = {}; \
    __builtin_amdgcn_s_setprio(1); \
    _Pragma("unroll") \
    for (int ni = 0; ni < 2; ++ni) \
      _Pragma("unroll") \
      for (int ks = 0; ks < 4; ++ks) { \
        bf16x8 kf = swzreadA(Ks[BUF], ni * 32 + l31, ks * 2 + h5); \
        s[ni] = __builtin_amdgcn_mfma_f32_32x32x16_bf16(kf, qf[ks], s[ni], 0, 0, 0); \
      } \
    __builtin_amdgcn_s_setprio(0); \
    float E[2][16]; \
    _Pragma("unroll") \
    for (int ni = 0; ni < 2; ++ni) \
      _Pragma("unroll") \
      for (int r = 0; r < 16; ++r) { \
        float e = vexp2(s[ni][r]); \
        E[ni][r] = e; \
        dv[r & 3] += e; \
      } \
    bf16x8 pa[4]; \
    _Pragma("unroll") \
    for (int ks = 0; ks < 4; ++ks) { \
      const int ni = ks >> 1, base = (ks & 1) * 8; \
      unsigned A0 = pack2(E[ni][base + 0], E[ni][base + 1]); \
      unsigned A1 = pack2(E[ni][base + 2], E[ni][base + 3]); \
      unsigned B0 = pack2(E[ni][base + 4], E[ni][base + 5]); \
      unsigned B1 = pack2(E[ni][base + 6], E[ni][base + 7]); \
      uint2v r0v = __builtin_amdgcn_permlane32_swap(A0, B0, false, false); \
      uint2v r1v = __builtin_amdgcn_permlane32_swap(A1, B1, false, false); \
      uint4v wv = {r0v[0], r1v[0], r0v[1], r1v[1]}; \
      pa[ks] = __builtin_bit_cast(bf16x8, wv); \
    } \
    __builtin_amdgcn_s_setprio(1); \
    _Pragma("unroll") \
    for (int ks = 0; ks < 4; ++ks) \
      _Pragma("unroll") \
      for (int di = 0; di < 2; ++di) { \
        bf16x8 vf = swzreadA(Vts[BUF], di * 32 + l31, ks * 2 + h5); \
        o_acc[di] = __builtin_amdgcn_mfma_f32_32x32x16_bf16(pa[ks], vf, o_acc[di], 0, 0, 0); \
      } \
    __builtin_amdgcn_s_setprio(0); \
    __syncthreads(); \
  } while (0)

  STAGE(0, kvb);
  __syncthreads();

  const int NT = SEQ / 128;            // 32 tiles of 64 kv
  for (int tt = 0; tt < NT; tt += 2) {
    TILE(0, true,           kvb + (tt + 1) * 64);
    TILE(1, (tt + 2) < NT,  kvb + (tt + 2) * 64);
  }

  // denominator: merge 4 chains, cross-half add, plain store per q.
  float den = (dv[0] + dv[1]) + (dv[2] + dv[3]);
  den += __shfl_xor(den, 32);
  if (lane < 32) lsum_part[(size_t)half * 16 * SEQ + (size_t)bh * SEQ + q0 + l31] = den;
  // partial-O: plain bf16 stores. PV D: col=lane&31=d, row q=(r&3)+8*(r>>2)+4*h5.
  __bf16* op = o_part + (size_t)half * MTOT * DIMC;
  #pragma unroll
  for (int di = 0; di < 2; ++di)
    #pragma unroll
    for (int r = 0; r < 16; ++r) {
      int q = q0 + (r & 3) + 8 * (r >> 2) + 4 * h5;
      op[(size_t)(b * SEQ + q) * DIMC + h * HDIM + di * 32 + l31] = (__bf16)o_acc[di][r];
    }
}

// ---------------- combine: o_ws = (o0+o1) / (l0+l1), bf16 ----------------
__global__ __launch_bounds__(256) void combine_o(const __bf16* __restrict__ o_part,
                                                 const float* __restrict__ lsum_part,
                                                 __bf16* __restrict__ o_ws) {
  int i = blockIdx.x * 256 + threadIdx.x;
  int flat = i * 8;
  int m = flat >> 8, c = flat & 255;
  int h = c >> 6;
  int b = m >> 12, p = m & 4095;
  size_t bhp = (size_t)(b * NHEADS + h) * SEQ + p;
  float inv = 1.f / (lsum_part[bhp] + lsum_part[(size_t)16 * SEQ + bhp]);
  bf16x8 a = *reinterpret_cast<const bf16x8*>(o_part + flat);
  bf16x8 bb = *reinterpret_cast<const bf16x8*>(o_part + (size_t)MTOT * DIMC + flat);
  bf16x8 o;
  #pragma unroll
  for (int j = 0; j < 8; ++j)
    o[j] = (__bf16)(((float)a[j] + (float)bb[j]) * inv);
  *reinterpret_cast<bf16x8*>(o_ws + flat) = o;
}

// ---------------- launch ----------------

extern "C" void kernel_launch(void* const* d_in, const int* in_sizes, int n_in,
                              void* d_out, int out_size, void* d_ws, size_t ws_size,
                              hipStream_t stream) {
  const float* x  = (const float*)d_in[0];
  const float* Wq = (const float*)d_in[1];
  const float* bq = (const float*)d_in[2];
  const float* Wk = (const float*)d_in[3];
  const float* bk = (const float*)d_in[4];
  const float* Wv = (const float*)d_in[5];
  const float* bv = (const float*)d_in[6];
  const float* Wo = (const float*)d_in[7];
  const float* bo = (const float*)d_in[8];
  float* out = (float*)d_out;

  const size_t NE = (size_t)MTOT * DIMC;  // 4,194,304 elements
  char* w = (char*)d_ws;
  __bf16* q_ws   = (__bf16*)w; w += NE * 2;
  __bf16* k_ws   = (__bf16*)w; w += NE * 2;
  __bf16* vt_ws  = (__bf16*)w; w += NE * 2;
  __bf16* wqkvt  = (__bf16*)w; w += (size_t)768 * 256 * 2;
  __bf16* wot    = (__bf16*)w; w += (size_t)256 * 256 * 2;
  float*  biasq  = (float*)w;  w += 768 * 4;
  float*  lsum_p = (float*)w;  w += (size_t)2 * 16 * SEQ * 4;  // 512 KB, plain stores
  __bf16* o_part = (__bf16*)w; w += 2 * NE * 2;                // 16 MB bf16 partials
  // aliases: xb lives in o_part (dead before attn writes); o_ws reuses q_ws.
  __bf16* xb   = o_part;
  __bf16* o_ws = q_ws;
  // total ws used: ~41.2 MB; NO memset needed (all buffers fully written).

  prep_all<<<5123, 256, 0, stream>>>(x, xb, Wq, Wk, Wv, Wo, bq, bk, bv, wqkvt, wot, biasq);
  gemm_bt<0><<<dim3(6, 128), 256, 0, stream>>>(xb, wqkvt, biasq, q_ws, k_ws, vt_ws, nullptr);
  attn_kernel<<<1024, 256, 0, stream>>>(q_ws, k_ws, vt_ws, o_part, lsum_p);
  combine_o<<<NE / 2048, 256, 0, stream>>>(o_part, lsum_p, o_ws);
  gemm_bt<1><<<dim3(2, 128), 256, 0, stream>>>(o_ws, wot, bo, nullptr, nullptr, nullptr, out);
}